// Round 2
// baseline (130.448 us; speedup 1.0000x reference)
//
#include <hip/hip_runtime.h>

#define L 1024
#define C 16
#define RT 128           // rows of M per block tile
#define JT 32            // j (columns) per LDS tile
#define MSTRIDE 36       // +4 floats pad: 16B-aligned rows, 4-way (not 32-way) on reads

__device__ __forceinline__ int lower_bound_i(const int* __restrict__ a, int n, int key) {
  int lo = 0, hi = n;
  while (lo < hi) {
    int mid = (lo + hi) >> 1;
    if (a[mid] < key) lo = mid + 1; else hi = mid;
  }
  return lo;
}

__global__ __launch_bounds__(128) void mp_kernel(
    const float* __restrict__ x,
    const float* __restrict__ M,
    const int*   __restrict__ batch,
    float*       __restrict__ out,
    int n_nodes)
{
  __shared__ float Mt[RT * MSTRIDE];   // 18 KB -> LDS never caps occupancy

  const int b  = blockIdx.y;
  const int sb = lower_bound_i(batch, n_nodes, b);
  const int se = lower_bound_i(batch, n_nodes, b + 1);
  int cnt = se - sb;
  if (cnt > L) cnt = L;
  const int r0 = blockIdx.x * RT;
  if (r0 >= cnt) return;              // uniform per block

  const float* Mb = M + (size_t)b * L * L;
  const float* xb = x + (size_t)sb * C;
  const int t  = threadIdx.x;         // 0..127
  const int cg = t & 1;               // channel group
  const int rl = t >> 1;              // 0..63: rows rl and rl+64
  const int c0 = cg * 8;

  float acc0[8] = {0.f,0.f,0.f,0.f,0.f,0.f,0.f,0.f};
  float acc1[8] = {0.f,0.f,0.f,0.f,0.f,0.f,0.f,0.f};

  const int njt = (cnt + JT - 1) / JT;

  // ---- T14 async staging: tile lives in regs one iteration ahead ----
  float4 sreg[8];
  #pragma unroll
  for (int p = 0; p < 8; ++p) {       // prologue: tile 0
    int f = p * 128 + t;              // 0..1023 over the 128x32 tile
    int row = f >> 3, cs = (f & 7) << 2;
    int gr = r0 + row;
    sreg[p] = (gr < cnt) ? *reinterpret_cast<const float4*>(Mb + (size_t)gr * L + cs)
                         : make_float4(0.f, 0.f, 0.f, 0.f);
  }

  for (int jt = 0; jt < njt; ++jt) {
    __syncthreads();                  // all waves done READING Mt (prev tile)
    #pragma unroll
    for (int p = 0; p < 8; ++p) {     // regs -> LDS (vmcnt wait inserted here)
      int f = p * 128 + t;
      int row = f >> 3, cs = (f & 7) << 2;
      *reinterpret_cast<float4*>(&Mt[row * MSTRIDE + cs]) = sreg[p];
    }
    if (jt + 1 < njt) {               // issue NEXT tile's loads: in flight
      int j0n = (jt + 1) * JT;        // across the whole compute phase
      #pragma unroll
      for (int p = 0; p < 8; ++p) {
        int f = p * 128 + t;
        int row = f >> 3, cs = (f & 7) << 2;
        int gr = r0 + row;
        sreg[p] = (gr < cnt)
            ? *reinterpret_cast<const float4*>(Mb + (size_t)gr * L + j0n + cs)
            : make_float4(0.f, 0.f, 0.f, 0.f);
      }
    }
    __syncthreads();                  // Mt tile ready

    const int j0 = jt * JT;
    #pragma unroll
    for (int j4 = 0; j4 < JT / 4; ++j4) {
      float4 ma = *reinterpret_cast<const float4*>(&Mt[rl * MSTRIDE + (j4 << 2)]);
      float4 mb = *reinterpret_cast<const float4*>(&Mt[(rl + 64) * MSTRIDE + (j4 << 2)]);
      #pragma unroll
      for (int jj = 0; jj < 4; ++jj) {
        const int j = j0 + (j4 << 2) + jj;
        // x straight from global: wave-uniform address -> 2 coalesced
        // transactions per load, L2-resident. Zero past cnt kills dead cols.
        float4 xlo, xhi;
        if (j < cnt) {
          xlo = *reinterpret_cast<const float4*>(xb + (size_t)j * C + c0);
          xhi = *reinterpret_cast<const float4*>(xb + (size_t)j * C + c0 + 4);
        } else {
          xlo = make_float4(0.f,0.f,0.f,0.f);
          xhi = make_float4(0.f,0.f,0.f,0.f);
        }
        float mja = (jj == 0) ? ma.x : (jj == 1) ? ma.y : (jj == 2) ? ma.z : ma.w;
        float mjb = (jj == 0) ? mb.x : (jj == 1) ? mb.y : (jj == 2) ? mb.z : mb.w;
        acc0[0] += mja * xlo.x; acc0[1] += mja * xlo.y;
        acc0[2] += mja * xlo.z; acc0[3] += mja * xlo.w;
        acc0[4] += mja * xhi.x; acc0[5] += mja * xhi.y;
        acc0[6] += mja * xhi.z; acc0[7] += mja * xhi.w;
        acc1[0] += mjb * xlo.x; acc1[1] += mjb * xlo.y;
        acc1[2] += mjb * xlo.z; acc1[3] += mjb * xlo.w;
        acc1[4] += mjb * xhi.x; acc1[5] += mjb * xhi.y;
        acc1[6] += mjb * xhi.z; acc1[7] += mjb * xhi.w;
      }
    }
  }

  // ---- epilogue: out[i, c] in original node order (i = sb + row) ----
  int ra = r0 + rl;
  if (ra < cnt) {
    float* o = out + (size_t)(sb + ra) * C + c0;
    *reinterpret_cast<float4*>(o)     = make_float4(acc0[0], acc0[1], acc0[2], acc0[3]);
    *reinterpret_cast<float4*>(o + 4) = make_float4(acc0[4], acc0[5], acc0[6], acc0[7]);
  }
  int rb = r0 + rl + 64;
  if (rb < cnt) {
    float* o = out + (size_t)(sb + rb) * C + c0;
    *reinterpret_cast<float4*>(o)     = make_float4(acc1[0], acc1[1], acc1[2], acc1[3]);
    *reinterpret_cast<float4*>(o + 4) = make_float4(acc1[4], acc1[5], acc1[6], acc1[7]);
  }
}

extern "C" void kernel_launch(void* const* d_in, const int* in_sizes, int n_in,
                              void* d_out, int out_size, void* d_ws, size_t ws_size,
                              hipStream_t stream) {
  const float* x     = (const float*)d_in[0];
  const float* M     = (const float*)d_in[1];
  const int*   batch = (const int*)d_in[2];
  float*       out   = (float*)d_out;
  const int n_nodes  = in_sizes[2];           // N = 65536
  const int B        = in_sizes[1] / (L * L); // 128
  dim3 grid(L / RT, B);
  mp_kernel<<<grid, dim3(128), 0, stream>>>(x, M, batch, out, n_nodes);
}

// Round 3
// 64.674 us; speedup vs baseline: 2.0170x; 2.0170x over previous
//
#include <hip/hip_runtime.h>

#define L 1024
#define C 16
#define RT 64            // rows of M per block
#define JT 32            // j (columns) per tile
#define MSTRIDE 36       // 36 floats = 144 B = 9*16 B: rows stay 16B-aligned, reads 2-way (free)

// lgkmcnt(0) + raw s_barrier: do NOT drain vmcnt (in-flight global prefetch
// targets wave-private VGPRs; no cross-wave visibility needed). __syncthreads()
// would emit s_waitcnt vmcnt(0) and kill the pipeline at every barrier.
__device__ __forceinline__ void block_sync_lds() {
  asm volatile("s_waitcnt lgkmcnt(0)" ::: "memory");
  __builtin_amdgcn_s_barrier();
}

// One tiny block: starts[i] = lower_bound(batch, i), i in [0, B]. Hoists the
// 17-dependent-load binary search out of all 2048 main-kernel blocks.
__global__ void starts_kernel(const int* __restrict__ batch, int n, int bp1,
                              int* __restrict__ starts) {
  int i = blockIdx.x * blockDim.x + threadIdx.x;
  if (i >= bp1) return;
  int lo = 0, hi = n;
  while (lo < hi) { int mid = (lo + hi) >> 1; if (batch[mid] < i) lo = mid + 1; else hi = mid; }
  starts[i] = lo;
}

__global__ __launch_bounds__(256) void mp_kernel(
    const float* __restrict__ x,
    const float* __restrict__ M,
    const int*   __restrict__ starts,
    float*       __restrict__ out)
{
  __shared__ float Mt[2][RT * MSTRIDE];  // 18 KB
  __shared__ float Xs[2][JT * C];        //  4 KB

  const int b  = blockIdx.y;
  const int sb = starts[b];
  int cnt = starts[b + 1] - sb;
  if (cnt > L) cnt = L;
  const int r0 = blockIdx.x * RT;
  if (r0 >= cnt) return;                 // uniform per block

  const float* Mb = M + (size_t)b * (L * L);
  const float* xb = x + (size_t)sb * C;
  const int t   = threadIdx.x;           // 0..255
  const int rl  = t >> 2;                // compute: row 0..63
  const int c0  = (t & 3) << 2;          // compute: 4 channels
  const int srow = t >> 3;               // stage: rows srow, srow+32
  const int scs  = (t & 7) << 2;         // stage: 4-float chunk in 32-col tile
  const int xj   = t >> 2;               // x stage (t<128): node in tile
  const int xcs  = (t & 3) << 2;

  const int njt = (cnt + JT - 1) / JT;

  float4 mreg0, mreg1, xreg;
  const float4 fz = make_float4(0.f, 0.f, 0.f, 0.f);

  auto issue = [&](int jt) {
    const int j0 = jt * JT;
    const int gr0 = r0 + srow, gr1 = gr0 + 32;
    // rows >= cnt zero-filled (their accs are discarded anyway; keeps LDS clean)
    mreg0 = (gr0 < cnt) ? *reinterpret_cast<const float4*>(Mb + (size_t)gr0 * L + j0 + scs) : fz;
    mreg1 = (gr1 < cnt) ? *reinterpret_cast<const float4*>(Mb + (size_t)gr1 * L + j0 + scs) : fz;
    if (t < 128)  // x zero past cnt: dead M columns contribute exactly 0
      xreg = (j0 + xj < cnt) ? *reinterpret_cast<const float4*>(xb + (size_t)(j0 + xj) * C + xcs) : fz;
  };
  auto write_lds = [&](int buf) {        // compiler inserts exact vmcnt waits here
    *reinterpret_cast<float4*>(&Mt[buf][srow * MSTRIDE + scs])        = mreg0;
    *reinterpret_cast<float4*>(&Mt[buf][(srow + 32) * MSTRIDE + scs]) = mreg1;
    if (t < 128)
      *reinterpret_cast<float4*>(&Xs[buf][xj * C + xcs]) = xreg;
  };

  float a0 = 0.f, a1 = 0.f, a2 = 0.f, a3 = 0.f;

  // prologue: tile 0 staged (one unavoidable vmcnt stall), tile 1 in flight
  issue(0);
  write_lds(0);
  if (njt > 1) issue(1);
  block_sync_lds();

  for (int jt = 0; jt < njt; ++jt) {
    const int cur = jt & 1;
    if (jt + 1 < njt) {
      write_lds(1 - cur);                // tile jt+1 (loads had full prev compute to land)
      if (jt + 2 < njt) issue(jt + 2);   // in flight across THIS compute + raw barrier
    }
    const float* mr = &Mt[cur][rl * MSTRIDE];
    #pragma unroll
    for (int j4 = 0; j4 < JT / 4; ++j4) {
      float4 m = *reinterpret_cast<const float4*>(mr + (j4 << 2));
      #pragma unroll
      for (int jj = 0; jj < 4; ++jj) {
        float4 xv = *reinterpret_cast<const float4*>(&Xs[cur][((j4 << 2) + jj) * C + c0]);
        float mj = (jj == 0) ? m.x : (jj == 1) ? m.y : (jj == 2) ? m.z : m.w;
        a0 += mj * xv.x; a1 += mj * xv.y; a2 += mj * xv.z; a3 += mj * xv.w;
      }
    }
    block_sync_lds();
  }

  const int ra = r0 + rl;
  if (ra < cnt) {                        // threads t consecutive -> contiguous 16B stores
    float* o = out + (size_t)(sb + ra) * C + c0;
    *reinterpret_cast<float4*>(o) = make_float4(a0, a1, a2, a3);
  }
}

extern "C" void kernel_launch(void* const* d_in, const int* in_sizes, int n_in,
                              void* d_out, int out_size, void* d_ws, size_t ws_size,
                              hipStream_t stream) {
  const float* x     = (const float*)d_in[0];
  const float* M     = (const float*)d_in[1];
  const int*   batch = (const int*)d_in[2];
  float*       out   = (float*)d_out;
  const int n_nodes  = in_sizes[2];            // N = 65536
  const int B        = in_sizes[1] / (L * L);  // 128
  int* starts = (int*)d_ws;                    // B+1 ints

  starts_kernel<<<1, 256, 0, stream>>>(batch, n_nodes, B + 1, starts);
  dim3 grid(L / RT, B);
  mp_kernel<<<grid, dim3(256), 0, stream>>>(x, M, starts, out);
}